// Round 2
// baseline (209.975 us; speedup 1.0000x reference)
//
#include <hip/hip_runtime.h>
#include <cstdint>
#include <cstddef>

// ---------------- types ----------------
typedef __attribute__((ext_vector_type(4))) float  floatx4;
typedef __attribute__((ext_vector_type(8))) __bf16 bf16x8;
typedef __attribute__((ext_vector_type(8))) unsigned short u16x8;

#define M_TOT 16384   // B*S
#define N_TOT 2048    // D_OUT
#define K_TOT 2048    // D_IN
#define NBATCH 8
#define RLORA 16
#define NT 32         // K tiles of 64

// f32 -> bf16 round-to-nearest-even
__device__ __forceinline__ unsigned short f32_to_bf16(float f) {
  unsigned u = __float_as_uint(f);
  u += 0x7fffu + ((u >> 16) & 1u);
  return (unsigned short)(u >> 16);
}

// async global->LDS, 16B per lane (LDS dest wave-uniform base + lane*16)
#define GLOAD_LDS16(gp, lp)                                                        \
  __builtin_amdgcn_global_load_lds((__attribute__((address_space(1))) void*)(void*)(gp), \
                                   (__attribute__((address_space(3))) void*)(void*)(lp), \
                                   16, 0, 0)

template<int V> struct IC { static constexpr int value = V; };

// ---------------- elementwise f32 -> bf16 (8 elems/thread) ----------------
__global__ void k_convert(const float* __restrict__ in, unsigned short* __restrict__ out, int n8) {
  int i = blockIdx.x * blockDim.x + threadIdx.x;
  if (i >= n8) return;
  const float4* p = (const float4*)in + (size_t)i * 2;
  float4 v0 = p[0], v1 = p[1];
  u16x8 o;
  o[0] = f32_to_bf16(v0.x); o[1] = f32_to_bf16(v0.y);
  o[2] = f32_to_bf16(v0.z); o[3] = f32_to_bf16(v0.w);
  o[4] = f32_to_bf16(v1.x); o[5] = f32_to_bf16(v1.y);
  o[6] = f32_to_bf16(v1.z); o[7] = f32_to_bf16(v1.w);
  *(u16x8*)(out + (size_t)i * 8) = o;
}

// ---------------- A_params [8][2048][16] f32 -> [8*2048][32] bf16, zero-padded ----------------
__global__ void k_convert_a(const float* __restrict__ A, unsigned short* __restrict__ abf) {
  int row = blockIdx.x * blockDim.x + threadIdx.x;
  if (row >= NBATCH * N_TOT) return;
  const float4* p = (const float4*)(A + (size_t)row * RLORA);
  float4 v0 = p[0], v1 = p[1], v2 = p[2], v3 = p[3];
  u16x8 lo, hi2, z = {0,0,0,0,0,0,0,0};
  lo[0] = f32_to_bf16(v0.x); lo[1] = f32_to_bf16(v0.y);
  lo[2] = f32_to_bf16(v0.z); lo[3] = f32_to_bf16(v0.w);
  lo[4] = f32_to_bf16(v1.x); lo[5] = f32_to_bf16(v1.y);
  lo[6] = f32_to_bf16(v1.z); lo[7] = f32_to_bf16(v1.w);
  hi2[0] = f32_to_bf16(v2.x); hi2[1] = f32_to_bf16(v2.y);
  hi2[2] = f32_to_bf16(v2.z); hi2[3] = f32_to_bf16(v2.w);
  hi2[4] = f32_to_bf16(v3.x); hi2[5] = f32_to_bf16(v3.y);
  hi2[6] = f32_to_bf16(v3.z); hi2[7] = f32_to_bf16(v3.w);
  u16x8* dst = (u16x8*)(abf + (size_t)row * 32);
  dst[0] = lo; dst[1] = hi2; dst[2] = z; dst[3] = z;
}

// ---------------- inter[m][r] = sum_i xbf[m][i] * bpbf[b][r][i] ----------------
__global__ __launch_bounds__(256) void k_inter(const unsigned short* __restrict__ xbf,
                                               const unsigned short* __restrict__ bpbf,
                                               unsigned short* __restrict__ interbf) {
  const int tid  = threadIdx.x;
  const int lane = tid & 63;
  const int wv   = tid >> 6;
  const int l15  = lane & 15;
  const int hi   = lane >> 4;
  const int m0   = blockIdx.x * 64;
  const int bb   = m0 >> 11;

  floatx4 zero = {0.f, 0.f, 0.f, 0.f};
  floatx4 acc[4] = {zero, zero, zero, zero};

  const unsigned short* bpb = bpbf + (size_t)bb * (RLORA * K_TOT);
  const int kb0 = wv * 512;
  for (int kb = kb0; kb < kb0 + 512; kb += 32) {
    bf16x8 bfr = *(const bf16x8*)(bpb + (size_t)l15 * K_TOT + kb + hi * 8);
    #pragma unroll
    for (int mi = 0; mi < 4; ++mi) {
      bf16x8 afr = *(const bf16x8*)(xbf + (size_t)(m0 + mi * 16 + l15) * K_TOT + kb + hi * 8);
      acc[mi] = __builtin_amdgcn_mfma_f32_16x16x32_bf16(afr, bfr, acc[mi], 0, 0, 0);
    }
  }

  __shared__ floatx4 red[4][4][64];
  #pragma unroll
  for (int mi = 0; mi < 4; ++mi) red[wv][mi][lane] = acc[mi];
  __syncthreads();
  if (wv == 0) {
    #pragma unroll
    for (int mi = 0; mi < 4; ++mi) {
      floatx4 s = red[0][mi][lane] + red[1][mi][lane] + red[2][mi][lane] + red[3][mi][lane];
      #pragma unroll
      for (int j = 0; j < 4; ++j) {
        int m = m0 + mi * 16 + hi * 4 + j;
        interbf[(size_t)m * 32 + l15] = f32_to_bf16(s[j]);
        interbf[(size_t)m * 32 + 16 + l15] = 0;
      }
    }
  }
}

// ---------------- main GEMM: 256x256 tile, BK=64, 8 waves, 8-phase counted-vmcnt pipeline ----
// LDS: 2 dbuf x 2 halves x [128][64] bf16 per operand = 128 KiB.
// Swizzle: chunk ^= (row&7), pre-swizzled global source + swizzled ds_read (0 conflicts, R1-verified).
// Staging schedule (death-order derived): tile t phases read buf=t&1;
//   quadrants (qm0,qn0),(qm0,qn1),(qm1,qn0),(qm1,qn1): B(buf) dead after ph2, A(buf) after ph3.
//   ph1 stages tile t+1's A1 (buf^1); ph3 stages tile t+2's B0,B1 (buf); ph4 stages t+2's A0 (buf).
//   vmcnt(6) (=3 half-tiles in flight) only at tile boundary => tile t+1 fully landed.
#define STAGE_A(bufi, h, tt) do {                                                      \
  GLOAD_LDS16(Ag + (h)*262144 + (tt)*64 + gOff0, AsB + ((bufi)*2+(h))*16384 + ldsB0);  \
  GLOAD_LDS16(Ag + (h)*262144 + (tt)*64 + gOff1, AsB + ((bufi)*2+(h))*16384 + ldsB1);  \
} while(0)
#define STAGE_B(bufi, h, tt) do {                                                      \
  GLOAD_LDS16(Bg + (h)*262144 + (tt)*64 + gOff0, BsB + ((bufi)*2+(h))*16384 + ldsB0);  \
  GLOAD_LDS16(Bg + (h)*262144 + (tt)*64 + gOff1, BsB + ((bufi)*2+(h))*16384 + ldsB1);  \
} while(0)
#define LDA(bufi, qm, mi, ks) (*(const bf16x8*)(AsB + ((bufi)*2 + wm)*16384 + \
  ((qm)*64 + (mi)*16 + l15)*128 + ((((ks)*4 + hi) ^ swz) * 16)))
#define LDB(bufi, ni, ks)     (*(const bf16x8*)(BsB + ((bufi)*2 + (wn>>1))*16384 + \
  (((wn&1)*64 + (ni)*16 + l15)*128 + ((((ks)*4 + hi) ^ swz) * 16))))

__global__ __launch_bounds__(512, 2) void k_gemm(const unsigned short* __restrict__ xbf,
                                                 const unsigned short* __restrict__ wbf,
                                                 const unsigned short* __restrict__ interbf,
                                                 const unsigned short* __restrict__ abf,
                                                 const float* __restrict__ bias,
                                                 float* __restrict__ out) {
  __shared__ unsigned short As[2][2][8192];
  __shared__ unsigned short Bs[2][2][8192];
  const int tid  = threadIdx.x;
  const int lane = tid & 63;
  const int wid  = tid >> 6;     // 0..7
  const int wm   = wid >> 2;     // 0..1
  const int wn   = wid & 3;      // 0..3
  const int l15  = lane & 15;
  const int hi   = lane >> 4;
  const int swz  = l15 & 7;

  // XCD-aware bijective swizzle: grid 512 = 64 mt x 8 nt, 512 % 8 == 0
  int bid  = blockIdx.x;
  int swzb = ((bid & 7) << 6) | (bid >> 3);
  const int mt = swzb >> 3;
  const int nt = swzb & 7;
  const int mrow0 = mt << 8;
  const int ncol0 = nt << 8;
  const int bb = mrow0 >> 11;    // batch (256 | 2048)

  const int m0 = mrow0 + wm * 128;
  const int n0 = ncol0 + wn * 64;

  const unsigned short* Ag = xbf + (size_t)mrow0 * K_TOT;
  const unsigned short* Bg = wbf + (size_t)ncol0 * K_TOT;
  char* AsB = (char*)As;
  char* BsB = (char*)Bs;

  // per-thread staging offsets (pre-swizzled source)
  const int r0    = tid >> 3;                 // 0..63
  const int k80   = (tid & 7) ^ (r0 & 7);
  const int gOff0 = r0 * K_TOT + k80 * 8;
  const int gOff1 = gOff0 + 64 * K_TOT;
  const int ldsB0 = wid * 1024;
  const int ldsB1 = 8192 + wid * 1024;

  // ---- LoRA adaptation as accumulator init (K=16 zero-padded to 32), overlapped with prologue staging
  floatx4 acc[8][4];
  {
    bf16x8 la[8], lb[4];
    #pragma unroll
    for (int mi = 0; mi < 8; ++mi)
      la[mi] = *(const bf16x8*)(interbf + (size_t)(m0 + mi * 16 + l15) * 32 + hi * 8);
    #pragma unroll
    for (int ni = 0; ni < 4; ++ni)
      lb[ni] = *(const bf16x8*)(abf + ((size_t)bb * N_TOT + n0 + ni * 16 + l15) * 32 + hi * 8);

    // prologue staging: tile0 {B0,B1,A0,A1}, tile1 {B0,B1,A0}  (issue order = steady-state order)
    STAGE_B(0, 0, 0); STAGE_B(0, 1, 0); STAGE_A(0, 0, 0); STAGE_A(0, 1, 0);
    STAGE_B(1, 0, 1); STAGE_B(1, 1, 1); STAGE_A(1, 0, 1);

    floatx4 z = {0.f, 0.f, 0.f, 0.f};
    #pragma unroll
    for (int mi = 0; mi < 8; ++mi)
      #pragma unroll
      for (int ni = 0; ni < 4; ++ni)
        acc[mi][ni] = __builtin_amdgcn_mfma_f32_16x16x32_bf16(la[mi], lb[ni], z, 0, 0, 0);
  }
  asm volatile("s_waitcnt vmcnt(6)" ::: "memory");   // tile0 landed; tile1 B0,B1,A0 in flight
  __builtin_amdgcn_s_barrier();

  auto tile = [&](int t, auto s1_, auto s2_, auto vm_) {
    constexpr int S1 = decltype(s1_)::value;   // stage t+1's A1 at phase 1
    constexpr int S2 = decltype(s2_)::value;   // stage t+2's B0,B1,A0 at phases 3,4
    constexpr int VM = decltype(vm_)::value;   // boundary vmcnt: 6, 0, or -1 (none)
    const int buf = t & 1;
    bf16x8 af[4][2], bfr[4][2];

    // ---- phase 1: quadrant (qm0, qn0) ----
    #pragma unroll
    for (int mi = 0; mi < 4; ++mi) { af[mi][0] = LDA(buf, 0, mi, 0); af[mi][1] = LDA(buf, 0, mi, 1); }
    #pragma unroll
    for (int ni = 0; ni < 2; ++ni) { bfr[ni][0] = LDB(buf, ni, 0); bfr[ni][1] = LDB(buf, ni, 1); }
    if constexpr (S1) STAGE_A(buf ^ 1, 1, t + 1);
    __builtin_amdgcn_s_barrier();
    asm volatile("s_waitcnt lgkmcnt(0)" ::: "memory");
    __builtin_amdgcn_s_setprio(1);
    #pragma unroll
    for (int mi = 0; mi < 4; ++mi)
      #pragma unroll
      for (int ni = 0; ni < 2; ++ni) {
        acc[mi][ni] = __builtin_amdgcn_mfma_f32_16x16x32_bf16(af[mi][0], bfr[ni][0], acc[mi][ni], 0, 0, 0);
        acc[mi][ni] = __builtin_amdgcn_mfma_f32_16x16x32_bf16(af[mi][1], bfr[ni][1], acc[mi][ni], 0, 0, 0);
      }
    __builtin_amdgcn_s_setprio(0);
    __builtin_amdgcn_s_barrier();

    // ---- phase 2: (qm0, qn1) ----
    #pragma unroll
    for (int ni = 0; ni < 2; ++ni) { bfr[2+ni][0] = LDB(buf, 2+ni, 0); bfr[2+ni][1] = LDB(buf, 2+ni, 1); }
    __builtin_amdgcn_s_barrier();
    asm volatile("s_waitcnt lgkmcnt(0)" ::: "memory");
    __builtin_amdgcn_s_setprio(1);
    #pragma unroll
    for (int mi = 0; mi < 4; ++mi)
      #pragma unroll
      for (int ni = 0; ni < 2; ++ni) {
        acc[mi][2+ni] = __builtin_amdgcn_mfma_f32_16x16x32_bf16(af[mi][0], bfr[2+ni][0], acc[mi][2+ni], 0, 0, 0);
        acc[mi][2+ni] = __builtin_amdgcn_mfma_f32_16x16x32_bf16(af[mi][1], bfr[2+ni][1], acc[mi][2+ni], 0, 0, 0);
      }
    __builtin_amdgcn_s_setprio(0);
    __builtin_amdgcn_s_barrier();

    // ---- phase 3: (qm1, qn0) ----  (B(buf) now dead -> stage t+2's B halves)
    #pragma unroll
    for (int mi = 0; mi < 4; ++mi) { af[mi][0] = LDA(buf, 1, mi, 0); af[mi][1] = LDA(buf, 1, mi, 1); }
    if constexpr (S2) { STAGE_B(buf, 0, t + 2); STAGE_B(buf, 1, t + 2); }
    __builtin_amdgcn_s_barrier();
    asm volatile("s_waitcnt lgkmcnt(0)" ::: "memory");
    __builtin_amdgcn_s_setprio(1);
    #pragma unroll
    for (int mi = 0; mi < 4; ++mi)
      #pragma unroll
      for (int ni = 0; ni < 2; ++ni) {
        acc[4+mi][ni] = __builtin_amdgcn_mfma_f32_16x16x32_bf16(af[mi][0], bfr[ni][0], acc[4+mi][ni], 0, 0, 0);
        acc[4+mi][ni] = __builtin_amdgcn_mfma_f32_16x16x32_bf16(af[mi][1], bfr[ni][1], acc[4+mi][ni], 0, 0, 0);
      }
    __builtin_amdgcn_s_setprio(0);
    __builtin_amdgcn_s_barrier();

    // ---- phase 4: (qm1, qn1) ----  (A(buf) now dead -> stage t+2's A0)
    if constexpr (S2) STAGE_A(buf, 0, t + 2);
    __builtin_amdgcn_s_barrier();
    asm volatile("s_waitcnt lgkmcnt(0)" ::: "memory");
    __builtin_amdgcn_s_setprio(1);
    #pragma unroll
    for (int mi = 0; mi < 4; ++mi)
      #pragma unroll
      for (int ni = 0; ni < 2; ++ni) {
        acc[4+mi][2+ni] = __builtin_amdgcn_mfma_f32_16x16x32_bf16(af[mi][0], bfr[2+ni][0], acc[4+mi][2+ni], 0, 0, 0);
        acc[4+mi][2+ni] = __builtin_amdgcn_mfma_f32_16x16x32_bf16(af[mi][1], bfr[2+ni][1], acc[4+mi][2+ni], 0, 0, 0);
      }
    __builtin_amdgcn_s_setprio(0);
    if constexpr (VM == 6)      asm volatile("s_waitcnt vmcnt(6)" ::: "memory");
    else if constexpr (VM == 0) asm volatile("s_waitcnt vmcnt(0)" ::: "memory");
    __builtin_amdgcn_s_barrier();
  };

  for (int t = 0; t < NT - 2; ++t) tile(t, IC<1>{}, IC<1>{}, IC<6>{});
  tile(NT - 2, IC<1>{}, IC<0>{}, IC<0>{});
  tile(NT - 1, IC<0>{}, IC<0>{}, IC<-1>{});

  // ---- epilogue: + bias, store f32 ----
  #pragma unroll
  for (int ni = 0; ni < 4; ++ni) {
    int col = n0 + ni * 16 + l15;
    float bv = bias[col];
    #pragma unroll
    for (int mi = 0; mi < 8; ++mi) {
      int r = m0 + mi * 16 + hi * 4;
      #pragma unroll
      for (int j = 0; j < 4; ++j)
        out[(size_t)(r + j) * N_TOT + col] = acc[mi][ni][j] + bv;
    }
  }
}

// ---------------- launcher ----------------
extern "C" void kernel_launch(void* const* d_in, const int* in_sizes, int n_in,
                              void* d_out, int out_size, void* d_ws, size_t ws_size,
                              hipStream_t stream) {
  const float* x    = (const float*)d_in[0];
  const float* Ap   = (const float*)d_in[1];
  const float* Bp   = (const float*)d_in[2];
  const float* W    = (const float*)d_in[3];
  const float* bias = (const float*)d_in[4];
  float* out = (float*)d_out;

  char* ws = (char*)d_ws;
  unsigned short* xbf     = (unsigned short*)(ws);
  unsigned short* wbf     = (unsigned short*)(ws + 67108864);
  unsigned short* abf     = (unsigned short*)(ws + 67108864 + 8388608);
  unsigned short* bpbf    = (unsigned short*)(ws + 67108864 + 8388608 + 1048576);
  unsigned short* interbf = (unsigned short*)(ws + 67108864 + 8388608 + 1048576 + 524288);

  k_convert<<<dim3(16384), dim3(256), 0, stream>>>(x,  xbf,  4194304);
  k_convert<<<dim3(2048),  dim3(256), 0, stream>>>(W,  wbf,   524288);
  k_convert<<<dim3(128),   dim3(256), 0, stream>>>(Bp, bpbf,   32768);
  k_convert_a<<<dim3(64),  dim3(256), 0, stream>>>(Ap, abf);

  k_inter<<<dim3(256), dim3(256), 0, stream>>>(xbf, bpbf, interbf);

  k_gemm<<<dim3(512), dim3(512), 0, stream>>>(xbf, wbf, interbf, abf, bias, out);
}

// Round 3
// 198.829 us; speedup vs baseline: 1.0561x; 1.0561x over previous
//
#include <hip/hip_runtime.h>
#include <cstdint>
#include <cstddef>

// ---------------- types ----------------
typedef __attribute__((ext_vector_type(4))) float  floatx4;
typedef __attribute__((ext_vector_type(8))) __bf16 bf16x8;
typedef __attribute__((ext_vector_type(8))) unsigned short u16x8;

#define M_TOT 16384   // B*S
#define N_TOT 2048    // D_OUT
#define K_TOT 2048    // D_IN
#define NBATCH 8
#define RLORA 16
#define NT 32         // K tiles of 64

// f32 -> bf16 round-to-nearest-even
__device__ __forceinline__ unsigned short f32_to_bf16(float f) {
  unsigned u = __float_as_uint(f);
  u += 0x7fffu + ((u >> 16) & 1u);
  return (unsigned short)(u >> 16);
}

// async global->LDS, 16B per lane (LDS dest wave-uniform base + lane*16)
#define GLOAD_LDS16(gp, lp)                                                        \
  __builtin_amdgcn_global_load_lds((__attribute__((address_space(1))) void*)(void*)(gp), \
                                   (__attribute__((address_space(3))) void*)(void*)(lp), \
                                   16, 0, 0)

template<int V> struct IC { static constexpr int value = V; };

// ---------------- elementwise f32 -> bf16 (8 elems/thread) ----------------
__global__ void k_convert(const float* __restrict__ in, unsigned short* __restrict__ out, int n8) {
  int i = blockIdx.x * blockDim.x + threadIdx.x;
  if (i >= n8) return;
  const float4* p = (const float4*)in + (size_t)i * 2;
  float4 v0 = p[0], v1 = p[1];
  u16x8 o;
  o[0] = f32_to_bf16(v0.x); o[1] = f32_to_bf16(v0.y);
  o[2] = f32_to_bf16(v0.z); o[3] = f32_to_bf16(v0.w);
  o[4] = f32_to_bf16(v1.x); o[5] = f32_to_bf16(v1.y);
  o[6] = f32_to_bf16(v1.z); o[7] = f32_to_bf16(v1.w);
  *(u16x8*)(out + (size_t)i * 8) = o;
}

// ---------------- A_params [8][2048][16] f32 -> [8*2048][32] bf16, zero-padded ----------------
__global__ void k_convert_a(const float* __restrict__ A, unsigned short* __restrict__ abf) {
  int row = blockIdx.x * blockDim.x + threadIdx.x;
  if (row >= NBATCH * N_TOT) return;
  const float4* p = (const float4*)(A + (size_t)row * RLORA);
  float4 v0 = p[0], v1 = p[1], v2 = p[2], v3 = p[3];
  u16x8 lo, hi2, z = {0,0,0,0,0,0,0,0};
  lo[0] = f32_to_bf16(v0.x); lo[1] = f32_to_bf16(v0.y);
  lo[2] = f32_to_bf16(v0.z); lo[3] = f32_to_bf16(v0.w);
  lo[4] = f32_to_bf16(v1.x); lo[5] = f32_to_bf16(v1.y);
  lo[6] = f32_to_bf16(v1.z); lo[7] = f32_to_bf16(v1.w);
  hi2[0] = f32_to_bf16(v2.x); hi2[1] = f32_to_bf16(v2.y);
  hi2[2] = f32_to_bf16(v2.z); hi2[3] = f32_to_bf16(v2.w);
  hi2[4] = f32_to_bf16(v3.x); hi2[5] = f32_to_bf16(v3.y);
  hi2[6] = f32_to_bf16(v3.z); hi2[7] = f32_to_bf16(v3.w);
  u16x8* dst = (u16x8*)(abf + (size_t)row * 32);
  dst[0] = lo; dst[1] = hi2; dst[2] = z; dst[3] = z;
}

// ---------------- inter[m][r] = sum_i xbf[m][i] * bpbf[b][r][i] ----------------
__global__ __launch_bounds__(256) void k_inter(const unsigned short* __restrict__ xbf,
                                               const unsigned short* __restrict__ bpbf,
                                               unsigned short* __restrict__ interbf) {
  const int tid  = threadIdx.x;
  const int lane = tid & 63;
  const int wv   = tid >> 6;
  const int l15  = lane & 15;
  const int hi   = lane >> 4;
  const int m0   = blockIdx.x * 64;
  const int bb   = m0 >> 11;

  floatx4 zero = {0.f, 0.f, 0.f, 0.f};
  floatx4 acc[4] = {zero, zero, zero, zero};

  const unsigned short* bpb = bpbf + (size_t)bb * (RLORA * K_TOT);
  const int kb0 = wv * 512;
  for (int kb = kb0; kb < kb0 + 512; kb += 32) {
    bf16x8 bfr = *(const bf16x8*)(bpb + (size_t)l15 * K_TOT + kb + hi * 8);
    #pragma unroll
    for (int mi = 0; mi < 4; ++mi) {
      bf16x8 afr = *(const bf16x8*)(xbf + (size_t)(m0 + mi * 16 + l15) * K_TOT + kb + hi * 8);
      acc[mi] = __builtin_amdgcn_mfma_f32_16x16x32_bf16(afr, bfr, acc[mi], 0, 0, 0);
    }
  }

  __shared__ floatx4 red[4][4][64];
  #pragma unroll
  for (int mi = 0; mi < 4; ++mi) red[wv][mi][lane] = acc[mi];
  __syncthreads();
  if (wv == 0) {
    #pragma unroll
    for (int mi = 0; mi < 4; ++mi) {
      floatx4 s = red[0][mi][lane] + red[1][mi][lane] + red[2][mi][lane] + red[3][mi][lane];
      #pragma unroll
      for (int j = 0; j < 4; ++j) {
        int m = m0 + mi * 16 + hi * 4 + j;
        interbf[(size_t)m * 32 + l15] = f32_to_bf16(s[j]);
        interbf[(size_t)m * 32 + 16 + l15] = 0;
      }
    }
  }
}

// ---------------- main GEMM: 256x256, BK=64, 8 waves, read-ahead 8-phase pipeline ----------------
// Fragment ds_reads are issued ONE PHASE AHEAD; MFMA waits via counted lgkmcnt, leaving the
// current slot's reads in flight (DS completes in-order per wave). vmcnt(4) once per tile at ph3.
// Quadrant (snake) order per tile: (qm0,qn0) (qm0,qn1) (qm1,qn1) (qm1,qn0).
// Slot plan: ph1-slot: bfS=B(buf,qn1)[4]; ph2-slot: afB=A(buf,qm1)[8]; ph3-slot: none;
//            ph4-slot: afA=A(buf^1,qm0)[8] + bfS=B(buf^1,qn0)[4]  (register roles P/Q swap per tile).
// Stages: ph1: A1(t+1)->buf^1; ph3: B0,B1(t+2)->buf; ph4: A0(t+2)->buf.
#define STAGE_A(bufi, h, tt) do {                                                      \
  GLOAD_LDS16(Ag + (h)*262144 + (tt)*64 + gOff0, AsB + ((bufi)*2+(h))*16384 + ldsB0);  \
  GLOAD_LDS16(Ag + (h)*262144 + (tt)*64 + gOff1, AsB + ((bufi)*2+(h))*16384 + ldsB1);  \
} while(0)
#define STAGE_B(bufi, h, tt) do {                                                      \
  GLOAD_LDS16(Bg + (h)*262144 + (tt)*64 + gOff0, BsB + ((bufi)*2+(h))*16384 + ldsB0);  \
  GLOAD_LDS16(Bg + (h)*262144 + (tt)*64 + gOff1, BsB + ((bufi)*2+(h))*16384 + ldsB1);  \
} while(0)
#define RDA_(B2, qm, mi, ks) (*(const bf16x8*)(AsB + (B2)*32768 + aBase + (qm)*8192 + (mi)*2048 + koff[ks]))
#define RDB_(B2, ni, ks)     (*(const bf16x8*)(BsB + (B2)*32768 + bBase + (ni)*2048 + koff[ks]))
#define BAR() __builtin_amdgcn_s_barrier()
// 16 MFMAs: acc[MB..MB+3][NB..NB+1] += AF x BF  (K=64 via ks-chained pairs)
#define MFMA16(MB, NB, AF, BF) do {                                                        \
  _Pragma("unroll")                                                                        \
  for (int mi = 0; mi < 4; ++mi) {                                                         \
    _Pragma("unroll")                                                                      \
    for (int j = 0; j < 2; ++j) {                                                          \
      acc[(MB)+mi][(NB)+j] = __builtin_amdgcn_mfma_f32_16x16x32_bf16(AF[mi][0], BF[j][0], acc[(MB)+mi][(NB)+j], 0, 0, 0); \
      acc[(MB)+mi][(NB)+j] = __builtin_amdgcn_mfma_f32_16x16x32_bf16(AF[mi][1], BF[j][1], acc[(MB)+mi][(NB)+j], 0, 0, 0); \
    }                                                                                      \
  }                                                                                        \
} while(0)

__global__ __launch_bounds__(512, 2) void k_gemm(const unsigned short* __restrict__ xbf,
                                                 const unsigned short* __restrict__ wbf,
                                                 const unsigned short* __restrict__ interbf,
                                                 const unsigned short* __restrict__ abf,
                                                 const float* __restrict__ bias,
                                                 float* __restrict__ out) {
  __shared__ unsigned short As[2][2][8192];
  __shared__ unsigned short Bs[2][2][8192];
  const int tid  = threadIdx.x;
  const int lane = tid & 63;
  const int wid  = tid >> 6;     // 0..7
  const int wm   = wid >> 2;     // 0..1
  const int wn   = wid & 3;      // 0..3
  const int l15  = lane & 15;
  const int hi   = lane >> 4;
  const int swz  = l15 & 7;

  // XCD-aware bijective swizzle: grid 512 = 64 mt x 8 nt
  int bid  = blockIdx.x;
  int swzb = ((bid & 7) << 6) | (bid >> 3);
  const int mt = swzb >> 3;
  const int nt = swzb & 7;
  const int mrow0 = mt << 8;
  const int ncol0 = nt << 8;
  const int bb = mrow0 >> 11;

  const int m0 = mrow0 + wm * 128;
  const int n0 = ncol0 + wn * 64;

  const unsigned short* Ag = xbf + (size_t)mrow0 * K_TOT;
  const unsigned short* Bg = wbf + (size_t)ncol0 * K_TOT;
  char* AsB = (char*)As;
  char* BsB = (char*)Bs;

  // staging offsets (pre-swizzled source; linear LDS dest)
  const int r0    = tid >> 3;
  const int k80   = (tid & 7) ^ (r0 & 7);
  const int gOff0 = r0 * K_TOT + k80 * 8;
  const int gOff1 = gOff0 + 64 * K_TOT;
  const int ldsB0 = wid * 1024;
  const int ldsB1 = 8192 + wid * 1024;

  // fragment read bases (byte offsets within As/Bs)
  const int aBase = wm * 16384 + l15 * 128;
  const int bBase = wn * 8192  + l15 * 128;
  int koff[2];
  koff[0] = ((0 * 4 + hi) ^ swz) * 16;
  koff[1] = ((1 * 4 + hi) ^ swz) * 16;

  floatx4 acc[8][4];
  bf16x8 afA[4][2], afB[4][2], bfP[2][2], bfQ[2][2];

  // ---- prologue: LoRA loads, stage 7 half-tiles, LoRA MFMA (drains only la/lb: issued oldest)
  {
    bf16x8 la[8], lb[4];
    #pragma unroll
    for (int mi = 0; mi < 8; ++mi)
      la[mi] = *(const bf16x8*)(interbf + (size_t)(m0 + mi * 16 + l15) * 32 + hi * 8);
    #pragma unroll
    for (int ni = 0; ni < 4; ++ni)
      lb[ni] = *(const bf16x8*)(abf + ((size_t)bb * N_TOT + n0 + ni * 16 + l15) * 32 + hi * 8);

    STAGE_B(0, 0, 0); STAGE_B(0, 1, 0); STAGE_A(0, 0, 0); STAGE_A(0, 1, 0);
    STAGE_B(1, 0, 1); STAGE_B(1, 1, 1); STAGE_A(1, 0, 1);

    floatx4 z = {0.f, 0.f, 0.f, 0.f};
    #pragma unroll
    for (int mi = 0; mi < 8; ++mi)
      #pragma unroll
      for (int ni = 0; ni < 4; ++ni)
        acc[mi][ni] = __builtin_amdgcn_mfma_f32_16x16x32_bf16(la[mi], lb[ni], z, 0, 0, 0);
  }
  asm volatile("s_waitcnt vmcnt(6)" ::: "memory");   // tile0 landed; tile1 B0,B1,A0 in flight
  BAR();
  // pre-slot: fragments for tile0 ph1
  #pragma unroll
  for (int mi = 0; mi < 4; ++mi) { afA[mi][0] = RDA_(0, 0, mi, 0); afA[mi][1] = RDA_(0, 0, mi, 1); }
  #pragma unroll
  for (int j = 0; j < 2; ++j)    { bfP[j][0]  = RDB_(0, j, 0);     bfP[j][1]  = RDB_(0, j, 1); }

  auto tile_step = [&](int t, auto bufc, auto s1c, auto s2c, auto vmc, auto lastc,
                       auto& bfF, auto& bfS) {
    constexpr int BUF  = decltype(bufc)::value;
    constexpr int S1   = decltype(s1c)::value;
    constexpr int S2   = decltype(s2c)::value;
    constexpr int VM   = decltype(vmc)::value;
    constexpr int LAST = decltype(lastc)::value;

    // ---- ph1: slot reads bfS = B(BUF, qn1); stage A1(t+1)->BUF^1; MFMA (qm0,qn0)
    #pragma unroll
    for (int j = 0; j < 2; ++j) { bfS[j][0] = RDB_(BUF, 2 + j, 0); bfS[j][1] = RDB_(BUF, 2 + j, 1); }
    if constexpr (S1) STAGE_A(BUF ^ 1, 1, t + 1);
    BAR();
    asm volatile("s_waitcnt lgkmcnt(4)" ::: "memory");
    __builtin_amdgcn_s_setprio(1);
    MFMA16(0, 0, afA, bfF);
    __builtin_amdgcn_s_setprio(0);
    BAR();

    // ---- ph2: slot reads afB = A(BUF, qm1); MFMA (qm0,qn1)
    #pragma unroll
    for (int mi = 0; mi < 4; ++mi) { afB[mi][0] = RDA_(BUF, 1, mi, 0); afB[mi][1] = RDA_(BUF, 1, mi, 1); }
    BAR();
    asm volatile("s_waitcnt lgkmcnt(8)" ::: "memory");
    __builtin_amdgcn_s_setprio(1);
    MFMA16(0, 2, afA, bfS);
    __builtin_amdgcn_s_setprio(0);
    BAR();

    // ---- ph3: no slot reads; stage B0,B1(t+2)->BUF; MFMA (qm1,qn1); vmcnt at end
    if constexpr (S2) { STAGE_B(BUF, 0, t + 2); STAGE_B(BUF, 1, t + 2); }
    BAR();
    asm volatile("s_waitcnt lgkmcnt(0)" ::: "memory");
    __builtin_amdgcn_s_setprio(1);
    MFMA16(4, 2, afB, bfS);
    __builtin_amdgcn_s_setprio(0);
    if constexpr (VM == 4)      asm volatile("s_waitcnt vmcnt(4)" ::: "memory");
    else if constexpr (VM == 0) asm volatile("s_waitcnt vmcnt(0)" ::: "memory");
    BAR();

    // ---- ph4: slot reads next tile's afA, bfS(=qn0 of BUF^1); stage A0(t+2)->BUF; MFMA (qm1,qn0)
    if constexpr (!LAST) {
      #pragma unroll
      for (int mi = 0; mi < 4; ++mi) { afA[mi][0] = RDA_(BUF ^ 1, 0, mi, 0); afA[mi][1] = RDA_(BUF ^ 1, 0, mi, 1); }
      #pragma unroll
      for (int j = 0; j < 2; ++j)    { bfS[j][0] = RDB_(BUF ^ 1, j, 0);      bfS[j][1] = RDB_(BUF ^ 1, j, 1); }
    }
    if constexpr (S2) STAGE_A(BUF, 0, t + 2);
    BAR();
    __builtin_amdgcn_s_setprio(1);
    MFMA16(4, 0, afB, bfF);
    __builtin_amdgcn_s_setprio(0);
    BAR();
  };

  for (int t = 0; t < NT - 2; t += 2) {
    tile_step(t,     IC<0>{}, IC<1>{}, IC<1>{}, IC<4>{}, IC<0>{}, bfP, bfQ);
    tile_step(t + 1, IC<1>{}, IC<1>{}, IC<1>{}, IC<4>{}, IC<0>{}, bfQ, bfP);
  }
  tile_step(NT - 2, IC<0>{}, IC<1>{}, IC<0>{}, IC<0>{},  IC<0>{}, bfP, bfQ);
  tile_step(NT - 1, IC<1>{}, IC<0>{}, IC<0>{}, IC<-1>{}, IC<1>{}, bfQ, bfP);

  // ---- epilogue: + bias, store f32 ----
  #pragma unroll
  for (int ni = 0; ni < 4; ++ni) {
    int col = n0 + ni * 16 + l15;
    float bv = bias[col];
    #pragma unroll
    for (int mi = 0; mi < 8; ++mi) {
      int r = m0 + mi * 16 + hi * 4;
      #pragma unroll
      for (int j = 0; j < 4; ++j)
        out[(size_t)(r + j) * N_TOT + col] = acc[mi][ni][j] + bv;
    }
  }
}

// ---------------- launcher ----------------
extern "C" void kernel_launch(void* const* d_in, const int* in_sizes, int n_in,
                              void* d_out, int out_size, void* d_ws, size_t ws_size,
                              hipStream_t stream) {
  const float* x    = (const float*)d_in[0];
  const float* Ap   = (const float*)d_in[1];
  const float* Bp   = (const float*)d_in[2];
  const float* W    = (const float*)d_in[3];
  const float* bias = (const float*)d_in[4];
  float* out = (float*)d_out;

  char* ws = (char*)d_ws;
  unsigned short* xbf     = (unsigned short*)(ws);
  unsigned short* wbf     = (unsigned short*)(ws + 67108864);
  unsigned short* abf     = (unsigned short*)(ws + 67108864 + 8388608);
  unsigned short* bpbf    = (unsigned short*)(ws + 67108864 + 8388608 + 1048576);
  unsigned short* interbf = (unsigned short*)(ws + 67108864 + 8388608 + 1048576 + 524288);

  k_convert<<<dim3(16384), dim3(256), 0, stream>>>(x,  xbf,  4194304);
  k_convert<<<dim3(2048),  dim3(256), 0, stream>>>(W,  wbf,   524288);
  k_convert<<<dim3(128),   dim3(256), 0, stream>>>(Bp, bpbf,   32768);
  k_convert_a<<<dim3(64),  dim3(256), 0, stream>>>(Ap, abf);

  k_inter<<<dim3(256), dim3(256), 0, stream>>>(xbf, bpbf, interbf);

  k_gemm<<<dim3(512), dim3(512), 0, stream>>>(xbf, wbf, interbf, abf, bias, out);
}